// Round 1
// baseline (152.823 us; speedup 1.0000x reference)
//
#include <hip/hip_runtime.h>
#include <hip/hip_bf16.h>
#include <math.h>

#define T_SEQ 2048
#define C_DIM 1024
#define H_DIM 64
#define N_BATCH 8
#define SCALE 0.125f
#define NTOK (N_BATCH * T_SEQ)   // 16384
#define NTILE 32                 // T_SEQ / 64
#define NCHUNK 4                 // R12: was 8; 4 blocks/CU suffices, halves
                                 // atomics + block prologues/epilogues
#define NU (NTILE / NCHUNK)      // 8 u-iterations max

// Journal:
// R2/R3: two-arg __launch_bounds__ => accumulator spill. Single-arg only.
// R4: scalar FMA latency-bound. MFMA everywhere. >=2 blocks/CU required.
// R7 FAILED (NaN): unexplained K-split; reverted, don't retry blind.
// R8: prefetch NEUTRAL. R9 WIN (proj W dedupe via LDS). R10 WIN (out K/V
//     staged + vprep transpose + 1/l folded into V). R11 WIN (proj x staged,
//     stats K/q staged). LAW: wins track scattered-vmem instrs removed.
// R10+: ~55us of dur_us is harness fill/restore (268MB d_ws poison @ ~6.4TB/s);
//     kernels sum ~100us and sit below the 41us top-5 visibility floor.
// R12: NCHUNK 8->4 (halve atomic traffic + block fixed costs), castw+zero merged.
// R13: proj fused across q/k/v: grid (256,3)->(256). x read ONCE (192MB->64MB;
//     proj compute floor is only ~0.8us, it's x-BW-bound). LDS 73.7KB dynamic
//     (Xt[2] + Wt[2][3]); 1 block/CU at grid=256 so occupancy unchanged.
//     Predicted dur 149.5 -> ~137. If neutral: proj was latency-bound, pivot
//     to kernel-count reduction (fold prep/vprep away) next.
// aff ~ N(0,1) => exp() can't overflow fp32; no max-shift needed.

typedef __attribute__((ext_vector_type(8))) short bf16x8;
typedef __attribute__((ext_vector_type(4))) float f32x4;

#define MFMA16(A, B, C) __builtin_amdgcn_mfma_f32_16x16x32_bf16(A, B, C, 0, 0, 0)

__device__ inline short f2bf(float f) {
    __hip_bfloat16 h = __float2bfloat16(f);
    return *reinterpret_cast<short*>(&h);
}
__device__ inline float bf2f(short s) {
    unsigned int u = ((unsigned int)(unsigned short)s) << 16;
    float f; __builtin_memcpy(&f, &u, 4);
    return f;
}

// ---------------------------------------------------------------------------
// prep: blocks 0..95 cast Wq/Wk/Wv fp32->bf16 packed [3][H*C];
//       blocks 96..1119 zero d_out (poisoned 0xAA; out_kernel atomicAdds).
// ---------------------------------------------------------------------------
__global__ __launch_bounds__(256) void prep_kernel(
    const float* __restrict__ Wq, const float* __restrict__ Wk,
    const float* __restrict__ Wv, short* __restrict__ Wb,
    float4* __restrict__ outz)
{
    if (blockIdx.x < 96) {
        const int total = H_DIM * C_DIM;           // 65536
        const int g = blockIdx.x * 256 + threadIdx.x;
        const int mat = g / (total / 8);
        const int idx = (g % (total / 8)) * 8;
        const float* s = (mat == 0) ? Wq : ((mat == 1) ? Wk : Wv);
        float4 a = *(const float4*)&s[idx];
        float4 b = *(const float4*)&s[idx + 4];
        bf16x8 o;
        o[0] = f2bf(a.x); o[1] = f2bf(a.y); o[2] = f2bf(a.z); o[3] = f2bf(a.w);
        o[4] = f2bf(b.x); o[5] = f2bf(b.y); o[6] = f2bf(b.z); o[7] = f2bf(b.w);
        *(bf16x8*)&Wb[(size_t)mat * total + idx] = o;
    } else {
        outz[(size_t)(blockIdx.x - 96) * 256 + threadIdx.x] =
            float4{0.f, 0.f, 0.f, 0.f};
    }
}

// ---------------------------------------------------------------------------
// Projection (R13: fused q/k/v). One block per 64-row x tile; x staged ONCE,
// all three W chunks staged per K-step; 24 MFMA/iter/wave into acc[3][4].
// q pre-scaled by SCALE (exact pow2 in bf16). FP order per matrix identical
// to the old per-which loop (bitwise-same outputs).
// ---------------------------------------------------------------------------
__global__ __launch_bounds__(256) void proj_kernel(
    const float* __restrict__ x, const short* __restrict__ Wb,
    short* __restrict__ qo, short* __restrict__ ko, short* __restrict__ vo)
{
    const int m0 = blockIdx.x * 64;
    const int tid = threadIdx.x;
    const int wave = tid >> 6, lane = tid & 63;
    const int l15 = lane & 15, quad = lane >> 4;

    // dynamic LDS: Xt[2][64][72] then Wt[2][3][64][72]  (73728 B total)
    extern __shared__ short smem[];
    short (*Xt)[64][72] = (short (*)[64][72])smem;
    short (*Wt)[3][64][72] = (short (*)[3][64][72])(smem + 2 * 64 * 72);

    const int sh = tid >> 3;
    const int sc = (tid & 7) * 8;

    f32x4 acc[3][4];
#pragma unroll
    for (int m = 0; m < 3; m++)
#pragma unroll
        for (int hg = 0; hg < 4; hg++) acc[m][hg] = f32x4{0.f, 0.f, 0.f, 0.f};

    {
#pragma unroll
        for (int m = 0; m < 3; m++) {
            const short* __restrict__ W = Wb + (size_t)m * (H_DIM * C_DIM);
            bf16x8 w0 = *(const bf16x8*)&W[(size_t)sh * C_DIM + sc];
            bf16x8 w1 = *(const bf16x8*)&W[(size_t)(sh + 32) * C_DIM + sc];
            *(bf16x8*)&Wt[0][m][sh][sc]      = w0;
            *(bf16x8*)&Wt[0][m][sh + 32][sc] = w1;
        }
#pragma unroll
        for (int j = 0; j < 4; j++) {
            const int f = tid + j * 256;
            const int row = f >> 4, c4 = f & 15;
            float4 xa = *(const float4*)&x[(size_t)(m0 + row) * C_DIM + c4 * 4];
            short o4[4];
            o4[0] = f2bf(xa.x); o4[1] = f2bf(xa.y);
            o4[2] = f2bf(xa.z); o4[3] = f2bf(xa.w);
            *(double*)&Xt[0][row][c4 * 4] = *(double*)o4;
        }
    }
    __syncthreads();

    for (int c0 = 0; c0 < C_DIM; c0 += 64) {
        const int bi = (c0 >> 6) & 1;
        const bool more = (c0 + 64 < C_DIM);

        bf16x8 nw[3][2];
        float4 nx[4];
        if (more) {
#pragma unroll
            for (int m = 0; m < 3; m++) {
                const short* __restrict__ W = Wb + (size_t)m * (H_DIM * C_DIM);
                nw[m][0] = *(const bf16x8*)&W[(size_t)sh * C_DIM + c0 + 64 + sc];
                nw[m][1] = *(const bf16x8*)&W[(size_t)(sh + 32) * C_DIM + c0 + 64 + sc];
            }
#pragma unroll
            for (int j = 0; j < 4; j++) {
                const int f = tid + j * 256;
                const int row = f >> 4, c4 = f & 15;
                nx[j] = *(const float4*)&x[(size_t)(m0 + row) * C_DIM + c0 + 64 + c4 * 4];
            }
        }

        bf16x8 a0 = *(const bf16x8*)&Xt[bi][wave * 16 + l15][quad * 8];
        bf16x8 a1 = *(const bf16x8*)&Xt[bi][wave * 16 + l15][32 + quad * 8];
#pragma unroll
        for (int m = 0; m < 3; m++)
#pragma unroll
            for (int hg = 0; hg < 4; hg++) {
                bf16x8 b0 = *(const bf16x8*)&Wt[bi][m][hg * 16 + l15][quad * 8];
                bf16x8 b1 = *(const bf16x8*)&Wt[bi][m][hg * 16 + l15][32 + quad * 8];
                acc[m][hg] = MFMA16(a0, b0, acc[m][hg]);
                acc[m][hg] = MFMA16(a1, b1, acc[m][hg]);
            }

        if (more) {
#pragma unroll
            for (int m = 0; m < 3; m++) {
                *(bf16x8*)&Wt[1 - bi][m][sh][sc]      = nw[m][0];
                *(bf16x8*)&Wt[1 - bi][m][sh + 32][sc] = nw[m][1];
            }
#pragma unroll
            for (int j = 0; j < 4; j++) {
                const int f = tid + j * 256;
                const int row = f >> 4, c4 = f & 15;
                short o4[4];
                o4[0] = f2bf(nx[j].x); o4[1] = f2bf(nx[j].y);
                o4[2] = f2bf(nx[j].z); o4[3] = f2bf(nx[j].w);
                *(double*)&Xt[1 - bi][row][c4 * 4] = *(double*)o4;
            }
        }
        __syncthreads();
    }

#pragma unroll
    for (int m = 0; m < 3; m++) {
        short* __restrict__ outp = (m == 0) ? qo : ((m == 1) ? ko : vo);
        const float osc = (m == 0) ? SCALE : 1.0f;
#pragma unroll
        for (int hg = 0; hg < 4; hg++)
#pragma unroll
            for (int r = 0; r < 4; r++) {
                const size_t row = m0 + wave * 16 + quad * 4 + r;
                outp[row * H_DIM + hg * 16 + l15] = f2bf(acc[m][hg][r] * osc);
            }
    }
}

// ---------------------------------------------------------------------------
// Stats: per key-column s, partial sum l = sum_{t>=s} exp(aff).
// NCHUNK=4: block (j0, chunk, b) visits tiles {chunk + u*4} ∩ [j0,32), u<8.
// ---------------------------------------------------------------------------
__global__ __launch_bounds__(256) void stats_kernel(
    const short* __restrict__ qg, const short* __restrict__ kg,
    float* __restrict__ pl)
{
    const int j0 = blockIdx.x, chunk = blockIdx.y, b = blockIdx.z;
    const int s0 = j0 * 64;
    const short* __restrict__ qb = qg + (size_t)b * T_SEQ * H_DIM;
    const short* __restrict__ kb = kg + (size_t)b * T_SEQ * H_DIM;
    const int tid = threadIdx.x, wave = tid >> 6, lane = tid & 63;
    const int l15 = lane & 15, quad = lane >> 4;

    __shared__ short Kt[64][72];
    __shared__ short Qt[2][64][72];
    __shared__ float sl[4][64];

    const int u0 = (j0 > chunk) ? ((j0 - chunk + NCHUNK - 1) / NCHUNK) : 0;

#pragma unroll
    for (int j = 0; j < 2; j++) {
        const int f = tid + j * 256;
        const int row = f >> 3, c8 = f & 7;
        *(bf16x8*)&Kt[row][c8 * 8] =
            *(const bf16x8*)&kb[(size_t)(s0 + row) * H_DIM + c8 * 8];
    }

    float lloc[4] = {0.f, 0.f, 0.f, 0.f};

    if (u0 < NU) {
        {
            const int t0 = (chunk + u0 * NCHUNK) * 64;
#pragma unroll
            for (int j = 0; j < 2; j++) {
                const int f = tid + j * 256;
                const int row = f >> 3, c8 = f & 7;
                *(bf16x8*)&Qt[0][row][c8 * 8] =
                    *(const bf16x8*)&qb[(size_t)(t0 + row) * H_DIM + c8 * 8];
            }
        }
        __syncthreads();

        for (int u = u0; u < NU; u++) {
            const int bi = (u - u0) & 1;
            const bool more = (u + 1 < NU);

            bf16x8 nq[2];
            if (more) {
                const int nt0 = (chunk + (u + 1) * NCHUNK) * 64;
#pragma unroll
                for (int j = 0; j < 2; j++) {
                    const int f = tid + j * 256;
                    const int row = f >> 3, c8 = f & 7;
                    nq[j] = *(const bf16x8*)&qb[(size_t)(nt0 + row) * H_DIM + c8 * 8];
                }
            }

            const int t0 = (chunk + u * NCHUNK) * 64;
            bf16x8 a0 = *(const bf16x8*)&Qt[bi][wave * 16 + l15][quad * 8];
            bf16x8 a1 = *(const bf16x8*)&Qt[bi][wave * 16 + l15][32 + quad * 8];
#pragma unroll
            for (int sg = 0; sg < 4; sg++) {
                bf16x8 k0 = *(const bf16x8*)&Kt[sg * 16 + l15][quad * 8];
                bf16x8 k1 = *(const bf16x8*)&Kt[sg * 16 + l15][32 + quad * 8];
                f32x4 c4 = f32x4{0.f, 0.f, 0.f, 0.f};
                c4 = MFMA16(a0, k0, c4);
                c4 = MFMA16(a1, k1, c4);
                const int s = s0 + sg * 16 + l15;
#pragma unroll
                for (int r = 0; r < 4; r++) {
                    const int t = t0 + wave * 16 + quad * 4 + r;
                    const float e = __expf(c4[r]);
                    lloc[sg] += (t >= s) ? e : 0.0f;
                }
            }

            if (more) {
#pragma unroll
                for (int j = 0; j < 2; j++) {
                    const int f = tid + j * 256;
                    const int row = f >> 3, c8 = f & 7;
                    *(bf16x8*)&Qt[1 - bi][row][c8 * 8] = nq[j];
                }
            }
            __syncthreads();
        }
    } else {
        __syncthreads();
    }

#pragma unroll
    for (int sg = 0; sg < 4; sg++) {
        lloc[sg] += __shfl_xor(lloc[sg], 16);
        lloc[sg] += __shfl_xor(lloc[sg], 32);
        if (quad == 0) sl[wave][sg * 16 + l15] = lloc[sg];
    }
    __syncthreads();
    if (tid < 64) {
        const float L = sl[0][tid] + sl[1][tid] + sl[2][tid] + sl[3][tid];
        pl[(size_t)chunk * NTOK + b * T_SEQ + s0 + tid] = L;
    }
}

// ---------------------------------------------------------------------------
// vprep: merge NCHUNK partial column sums, scale V rows by 1/L, write V'
// transposed to global vT [b][h][t].
// ---------------------------------------------------------------------------
__global__ __launch_bounds__(256) void vprep_kernel(
    const float* __restrict__ pl, const short* __restrict__ vg,
    short* __restrict__ vTg)
{
    const int j0 = blockIdx.x;
    const int b  = blockIdx.y;
    const int s0 = j0 * 64;
    const int tid = threadIdx.x;

    __shared__ float lrec[64];
    __shared__ short Tt[64][72];

    if (tid < 64) {
        const int col = b * T_SEQ + s0 + tid;
        float L = 0.f;
#pragma unroll
        for (int c = 0; c < NCHUNK; c++) L += pl[(size_t)c * NTOK + col];
        lrec[tid] = 1.0f / L;
    }
    __syncthreads();

    const int sr = tid >> 3;
    const int sc = (tid & 7) * 8;
#pragma unroll
    for (int hh = 0; hh < 2; hh++) {
        const int s = sr + hh * 32;
        bf16x8 v = *(const bf16x8*)&vg[(size_t)(b * T_SEQ + s0 + s) * H_DIM + sc];
        const float li = lrec[s];
        bf16x8 o;
#pragma unroll
        for (int d = 0; d < 8; d++) o[d] = f2bf(bf2f(v[d]) * li);
        *(bf16x8*)&Tt[s][sc] = o;
    }
    __syncthreads();

#pragma unroll
    for (int hh = 0; hh < 2; hh++) {
        const int h = sr + hh * 32;
        bf16x8 o;
#pragma unroll
        for (int d = 0; d < 8; d++) o[d] = Tt[sc + d][h];
        *(bf16x8*)&vTg[(size_t)(b * H_DIM + h) * T_SEQ + s0 + sc] = o;
    }
}

// ---------------------------------------------------------------------------
// Output (R10 structure; NCHUNK=4 => up to 8 u-iters, half the atomics).
// ---------------------------------------------------------------------------
__global__ __launch_bounds__(256) void out_kernel(
    const short* __restrict__ qg, const short* __restrict__ kg,
    const short* __restrict__ vTg, float* __restrict__ outg)
{
    const int i0 = blockIdx.x, chunk = blockIdx.y, b = blockIdx.z;
    if (chunk > i0) return;
    const int t0 = i0 * 64;
    const short* __restrict__ qb  = qg  + (size_t)b * T_SEQ * H_DIM;
    const short* __restrict__ kb  = kg  + (size_t)b * T_SEQ * H_DIM;
    const short* __restrict__ vTb = vTg + (size_t)b * H_DIM * T_SEQ;
    const int tid = threadIdx.x, wave = tid >> 6, lane = tid & 63;
    const int l15 = lane & 15, quad = lane >> 4;

    __shared__ short Kt[2][64][72];
    __shared__ short Vt[2][64][72];
    __shared__ short PW[4][16][72];

    const int sh = tid >> 3;
    const int sc = (tid & 7) * 8;

    const short* qr = &qb[(size_t)(t0 + wave * 16 + l15) * H_DIM + quad * 8];
    const bf16x8 qa0 = *(const bf16x8*)qr;
    const bf16x8 qa1 = *(const bf16x8*)(qr + 32);

    f32x4 oacc[4];
#pragma unroll
    for (int hg = 0; hg < 4; hg++) oacc[hg] = f32x4{0.f, 0.f, 0.f, 0.f};

    {
        const int s0 = chunk * 64;
        *(bf16x8*)&Kt[0][sh][sc]      = *(const bf16x8*)&kb[(size_t)(s0 + sh) * H_DIM + sc];
        *(bf16x8*)&Kt[0][sh + 32][sc] = *(const bf16x8*)&kb[(size_t)(s0 + sh + 32) * H_DIM + sc];
        *(bf16x8*)&Vt[0][sh][sc]      = *(const bf16x8*)&vTb[(size_t)sh * T_SEQ + s0 + sc];
        *(bf16x8*)&Vt[0][sh + 32][sc] = *(const bf16x8*)&vTb[(size_t)(sh + 32) * T_SEQ + s0 + sc];
    }
    __syncthreads();

    for (int u = 0; u < NU; u++) {
        const int js = chunk + u * NCHUNK;
        if (js > i0) break;            // uniform per block
        const int s0 = js * 64;
        const int bi = u & 1;
        const bool more = (js + NCHUNK <= i0);

        bf16x8 nk0, nk1, nv0, nv1;
        if (more) {
            const int ns0 = s0 + NCHUNK * 64;
            nk0 = *(const bf16x8*)&kb[(size_t)(ns0 + sh) * H_DIM + sc];
            nk1 = *(const bf16x8*)&kb[(size_t)(ns0 + sh + 32) * H_DIM + sc];
            nv0 = *(const bf16x8*)&vTb[(size_t)sh * T_SEQ + ns0 + sc];
            nv1 = *(const bf16x8*)&vTb[(size_t)(sh + 32) * T_SEQ + ns0 + sc];
        }

        f32x4 c4[4];
#pragma unroll
        for (int sg = 0; sg < 4; sg++) {
            bf16x8 k0 = *(const bf16x8*)&Kt[bi][sg * 16 + l15][quad * 8];
            bf16x8 k1 = *(const bf16x8*)&Kt[bi][sg * 16 + l15][32 + quad * 8];
            f32x4 z = f32x4{0.f, 0.f, 0.f, 0.f};
            z = MFMA16(qa0, k0, z);
            z = MFMA16(qa1, k1, z);
            c4[sg] = z;
        }
#pragma unroll
        for (int sg = 0; sg < 4; sg++) {
            const int s = s0 + sg * 16 + l15;
#pragma unroll
            for (int r = 0; r < 4; r++) {
                const int t = t0 + wave * 16 + quad * 4 + r;
                const float p = (s <= t) ? __expf(c4[sg][r]) : 0.0f;
                PW[wave][quad * 4 + r][sg * 16 + l15] = f2bf(p);
            }
        }
        __syncthreads();

        const bf16x8 pa0 = *(const bf16x8*)&PW[wave][l15][quad * 8];
        const bf16x8 pa1 = *(const bf16x8*)&PW[wave][l15][32 + quad * 8];
#pragma unroll
        for (int hg = 0; hg < 4; hg++) {
            bf16x8 v0 = *(const bf16x8*)&Vt[bi][hg * 16 + l15][quad * 8];
            bf16x8 v1 = *(const bf16x8*)&Vt[bi][hg * 16 + l15][32 + quad * 8];
            oacc[hg] = MFMA16(pa0, v0, oacc[hg]);
            oacc[hg] = MFMA16(pa1, v1, oacc[hg]);
        }

        if (more) {
            *(bf16x8*)&Kt[1 - bi][sh][sc]      = nk0;
            *(bf16x8*)&Kt[1 - bi][sh + 32][sc] = nk1;
            *(bf16x8*)&Vt[1 - bi][sh][sc]      = nv0;
            *(bf16x8*)&Vt[1 - bi][sh + 32][sc] = nv1;
        }
        __syncthreads();
    }

#pragma unroll
    for (int hg = 0; hg < 4; hg++)
#pragma unroll
        for (int r = 0; r < 4; r++) {
            const int t = t0 + wave * 16 + quad * 4 + r;
            atomicAdd(&outg[(size_t)(b * T_SEQ + t) * H_DIM + hg * 16 + l15],
                      oacc[hg][r]);
        }
}

// ---------------------------------------------------------------------------
extern "C" void kernel_launch(void* const* d_in, const int* in_sizes, int n_in,
                              void* d_out, int out_size, void* d_ws, size_t ws_size,
                              hipStream_t stream) {
    const float* x  = (const float*)d_in[0];
    const float* Wq = (const float*)d_in[1];
    const float* Wk = (const float*)d_in[2];
    const float* Wv = (const float*)d_in[3];
    float* out = (float*)d_out;

    float* w = (float*)d_ws;
    float* pl = w;                            // NCHUNK*NTOK
    short* qb = (short*)(pl + (size_t)NCHUNK * NTOK);
    short* kb = qb + (size_t)NTOK * H_DIM;
    short* vb = kb + (size_t)NTOK * H_DIM;
    short* Wb = vb + (size_t)NTOK * H_DIM;    // [3][H*C]
    short* vT = Wb + (size_t)3 * H_DIM * C_DIM;  // [B][H][T]

    prep_kernel<<<96 + (NTOK * H_DIM / 4) / 256, 256, 0, stream>>>(
        Wq, Wk, Wv, Wb, (float4*)out);
    // R13: fused proj; dynamic LDS = Xt[2][64][72] + Wt[2][3][64][72] shorts
    const size_t proj_lds = (size_t)(2 * 64 * 72 + 2 * 3 * 64 * 72) * sizeof(short);
    proj_kernel<<<256, 256, proj_lds, stream>>>(x, Wb, qb, kb, vb);
    stats_kernel<<<dim3(NTILE, NCHUNK, N_BATCH), 256, 0, stream>>>(qb, kb, pl);
    vprep_kernel<<<dim3(NTILE, N_BATCH), 256, 0, stream>>>(pl, vb, vT);
    out_kernel<<<dim3(NTILE, NCHUNK, N_BATCH), 256, 0, stream>>>(qb, kb, vT, out);
}

// Round 2
// 150.008 us; speedup vs baseline: 1.0188x; 1.0188x over previous
//
#include <hip/hip_runtime.h>
#include <hip/hip_bf16.h>
#include <math.h>

#define T_SEQ 2048
#define C_DIM 1024
#define H_DIM 64
#define N_BATCH 8
#define SCALE 0.125f
#define NTOK (N_BATCH * T_SEQ)   // 16384
#define NTILE 32                 // T_SEQ / 64
#define NCHUNK 4                 // R12: was 8; 4 blocks/CU suffices, halves
                                 // atomics + block prologues/epilogues
#define NU (NTILE / NCHUNK)      // 8 u-iterations max

// Journal:
// R2/R3: two-arg __launch_bounds__ => accumulator spill. Single-arg only.
// R4: scalar FMA latency-bound. MFMA everywhere. >=2 blocks/CU required.
// R7 FAILED (NaN): unexplained K-split; reverted, don't retry blind.
// R8: prefetch NEUTRAL. R9 WIN (proj W dedupe via LDS). R10 WIN (out K/V
//     staged + vprep transpose + 1/l folded into V). R11 WIN (proj x staged,
//     stats K/q staged). LAW: wins track scattered-vmem instrs removed.
// R10+: ~55us of dur_us is harness fill/restore (268MB d_ws poison @ ~6.4TB/s);
//     kernels sum ~100us and sit below the 41us top-5 visibility floor.
// R12: NCHUNK 8->4 (halve atomic traffic + block fixed costs), castw+zero merged.
// R13 NEUTRAL-NEG (149.5->152.8): fused proj x-read win was L3-read not HBM
//     (old (256,3) grid ran same-tile blocks adjacently -> L3 hits); occupancy
//     fell 3 blocks/CU -> 1 wave/SIMD, exposing ~900cyc cold-HBM x latency.
// R14: keep fusion, restore occupancy: 768 thr / 12 waves (3/SIMD), wave ->
//     (m, rowgroup). Same FP order, acc[4]/thread. Predict ~140-145us; if
//     ~149-150, proj is prefetch-depth-limited -> 2-deep x prefetch next.
// aff ~ N(0,1) => exp() can't overflow fp32; no max-shift needed.

typedef __attribute__((ext_vector_type(8))) short bf16x8;
typedef __attribute__((ext_vector_type(4))) float f32x4;

#define MFMA16(A, B, C) __builtin_amdgcn_mfma_f32_16x16x32_bf16(A, B, C, 0, 0, 0)

__device__ inline short f2bf(float f) {
    __hip_bfloat16 h = __float2bfloat16(f);
    return *reinterpret_cast<short*>(&h);
}
__device__ inline float bf2f(short s) {
    unsigned int u = ((unsigned int)(unsigned short)s) << 16;
    float f; __builtin_memcpy(&f, &u, 4);
    return f;
}

// ---------------------------------------------------------------------------
// prep: blocks 0..95 cast Wq/Wk/Wv fp32->bf16 packed [3][H*C];
//       blocks 96..1119 zero d_out (poisoned 0xAA; out_kernel atomicAdds).
// ---------------------------------------------------------------------------
__global__ __launch_bounds__(256) void prep_kernel(
    const float* __restrict__ Wq, const float* __restrict__ Wk,
    const float* __restrict__ Wv, short* __restrict__ Wb,
    float4* __restrict__ outz)
{
    if (blockIdx.x < 96) {
        const int total = H_DIM * C_DIM;           // 65536
        const int g = blockIdx.x * 256 + threadIdx.x;
        const int mat = g / (total / 8);
        const int idx = (g % (total / 8)) * 8;
        const float* s = (mat == 0) ? Wq : ((mat == 1) ? Wk : Wv);
        float4 a = *(const float4*)&s[idx];
        float4 b = *(const float4*)&s[idx + 4];
        bf16x8 o;
        o[0] = f2bf(a.x); o[1] = f2bf(a.y); o[2] = f2bf(a.z); o[3] = f2bf(a.w);
        o[4] = f2bf(b.x); o[5] = f2bf(b.y); o[6] = f2bf(b.z); o[7] = f2bf(b.w);
        *(bf16x8*)&Wb[(size_t)mat * total + idx] = o;
    } else {
        outz[(size_t)(blockIdx.x - 96) * 256 + threadIdx.x] =
            float4{0.f, 0.f, 0.f, 0.f};
    }
}

// ---------------------------------------------------------------------------
// Projection (R14: fused q/k/v, 768 threads / 12 waves = 3 waves/SIMD).
// One block per 64-row x tile; x staged ONCE; wave w owns matrix m=w/4,
// row-group w%4 => 8 MFMA/wave/K-step (96 total, same as R12/R13 work).
// q pre-scaled by SCALE (exact pow2 in bf16). FP order per output element
// identical to R12 (bitwise-same outputs).
// ---------------------------------------------------------------------------
__global__ __launch_bounds__(768) void proj_kernel(
    const float* __restrict__ x, const short* __restrict__ Wb,
    short* __restrict__ qo, short* __restrict__ ko, short* __restrict__ vo)
{
    const int m0 = blockIdx.x * 64;
    const int tid = threadIdx.x;
    const int wave = tid >> 6, lane = tid & 63;
    const int l15 = lane & 15, quad = lane >> 4;
    const int m  = wave >> 2;   // matrix 0..2
    const int rg = wave & 3;    // row-group 0..3

    // dynamic LDS: Xt[2][64][72] then Wt[2][3][64][72]  (73728 B total)
    extern __shared__ short smem[];
    short (*Xt)[64][72] = (short (*)[64][72])smem;
    short (*Wt)[3][64][72] = (short (*)[3][64][72])(smem + 2 * 64 * 72);

    f32x4 acc[4];
#pragma unroll
    for (int hg = 0; hg < 4; hg++) acc[hg] = f32x4{0.f, 0.f, 0.f, 0.f};

    // ---- prologue stage (buffer 0, c0 = 0) ----
    {
        // W: 3 mats x 64 rows x 64 cols = 1536 bf16x8 loads, 768 thr x 2
#pragma unroll
        for (int j = 0; j < 2; j++) {
            const int f = tid + j * 768;
            const int wmat = f >> 9;            // 512 loads per matrix
            const int wrow = (f >> 3) & 63;
            const int wc8  = f & 7;
            bf16x8 w = *(const bf16x8*)&Wb[(size_t)wmat * (H_DIM * C_DIM)
                                           + (size_t)wrow * C_DIM + wc8 * 8];
            *(bf16x8*)&Wt[0][wmat][wrow][wc8 * 8] = w;
        }
        // X: 64 rows x 64 cols fp32 = 1024 float4 loads, threads 0..511 x 2
        if (tid < 512) {
#pragma unroll
            for (int j = 0; j < 2; j++) {
                const int f = tid + j * 512;
                const int row = f >> 4, c4 = f & 15;
                float4 xa = *(const float4*)&x[(size_t)(m0 + row) * C_DIM + c4 * 4];
                short o4[4];
                o4[0] = f2bf(xa.x); o4[1] = f2bf(xa.y);
                o4[2] = f2bf(xa.z); o4[3] = f2bf(xa.w);
                *(double*)&Xt[0][row][c4 * 4] = *(double*)o4;
            }
        }
    }
    __syncthreads();

    for (int c0 = 0; c0 < C_DIM; c0 += 64) {
        const int bi = (c0 >> 6) & 1;
        const bool more = (c0 + 64 < C_DIM);

        bf16x8 nw[2];
        float4 nx[2];
        if (more) {
#pragma unroll
            for (int j = 0; j < 2; j++) {
                const int f = tid + j * 768;
                const int wmat = f >> 9;
                const int wrow = (f >> 3) & 63;
                const int wc8  = f & 7;
                nw[j] = *(const bf16x8*)&Wb[(size_t)wmat * (H_DIM * C_DIM)
                                            + (size_t)wrow * C_DIM + c0 + 64 + wc8 * 8];
            }
            if (tid < 512) {
#pragma unroll
                for (int j = 0; j < 2; j++) {
                    const int f = tid + j * 512;
                    const int row = f >> 4, c4 = f & 15;
                    nx[j] = *(const float4*)&x[(size_t)(m0 + row) * C_DIM + c0 + 64 + c4 * 4];
                }
            }
        }

        bf16x8 a0 = *(const bf16x8*)&Xt[bi][rg * 16 + l15][quad * 8];
        bf16x8 a1 = *(const bf16x8*)&Xt[bi][rg * 16 + l15][32 + quad * 8];
#pragma unroll
        for (int hg = 0; hg < 4; hg++) {
            bf16x8 b0 = *(const bf16x8*)&Wt[bi][m][hg * 16 + l15][quad * 8];
            bf16x8 b1 = *(const bf16x8*)&Wt[bi][m][hg * 16 + l15][32 + quad * 8];
            acc[hg] = MFMA16(a0, b0, acc[hg]);
            acc[hg] = MFMA16(a1, b1, acc[hg]);
        }

        if (more) {
#pragma unroll
            for (int j = 0; j < 2; j++) {
                const int f = tid + j * 768;
                const int wmat = f >> 9;
                const int wrow = (f >> 3) & 63;
                const int wc8  = f & 7;
                *(bf16x8*)&Wt[1 - bi][wmat][wrow][wc8 * 8] = nw[j];
            }
            if (tid < 512) {
#pragma unroll
                for (int j = 0; j < 2; j++) {
                    const int f = tid + j * 512;
                    const int row = f >> 4, c4 = f & 15;
                    short o4[4];
                    o4[0] = f2bf(nx[j].x); o4[1] = f2bf(nx[j].y);
                    o4[2] = f2bf(nx[j].z); o4[3] = f2bf(nx[j].w);
                    *(double*)&Xt[1 - bi][row][c4 * 4] = *(double*)o4;
                }
            }
        }
        __syncthreads();
    }

    {
        short* __restrict__ outp = (m == 0) ? qo : ((m == 1) ? ko : vo);
        const float osc = (m == 0) ? SCALE : 1.0f;
#pragma unroll
        for (int hg = 0; hg < 4; hg++)
#pragma unroll
            for (int r = 0; r < 4; r++) {
                const size_t row = m0 + rg * 16 + quad * 4 + r;
                outp[row * H_DIM + hg * 16 + l15] = f2bf(acc[hg][r] * osc);
            }
    }
}

// ---------------------------------------------------------------------------
// Stats: per key-column s, partial sum l = sum_{t>=s} exp(aff).
// NCHUNK=4: block (j0, chunk, b) visits tiles {chunk + u*4} ∩ [j0,32), u<8.
// ---------------------------------------------------------------------------
__global__ __launch_bounds__(256) void stats_kernel(
    const short* __restrict__ qg, const short* __restrict__ kg,
    float* __restrict__ pl)
{
    const int j0 = blockIdx.x, chunk = blockIdx.y, b = blockIdx.z;
    const int s0 = j0 * 64;
    const short* __restrict__ qb = qg + (size_t)b * T_SEQ * H_DIM;
    const short* __restrict__ kb = kg + (size_t)b * T_SEQ * H_DIM;
    const int tid = threadIdx.x, wave = tid >> 6, lane = tid & 63;
    const int l15 = lane & 15, quad = lane >> 4;

    __shared__ short Kt[64][72];
    __shared__ short Qt[2][64][72];
    __shared__ float sl[4][64];

    const int u0 = (j0 > chunk) ? ((j0 - chunk + NCHUNK - 1) / NCHUNK) : 0;

#pragma unroll
    for (int j = 0; j < 2; j++) {
        const int f = tid + j * 256;
        const int row = f >> 3, c8 = f & 7;
        *(bf16x8*)&Kt[row][c8 * 8] =
            *(const bf16x8*)&kb[(size_t)(s0 + row) * H_DIM + c8 * 8];
    }

    float lloc[4] = {0.f, 0.f, 0.f, 0.f};

    if (u0 < NU) {
        {
            const int t0 = (chunk + u0 * NCHUNK) * 64;
#pragma unroll
            for (int j = 0; j < 2; j++) {
                const int f = tid + j * 256;
                const int row = f >> 3, c8 = f & 7;
                *(bf16x8*)&Qt[0][row][c8 * 8] =
                    *(const bf16x8*)&qb[(size_t)(t0 + row) * H_DIM + c8 * 8];
            }
        }
        __syncthreads();

        for (int u = u0; u < NU; u++) {
            const int bi = (u - u0) & 1;
            const bool more = (u + 1 < NU);

            bf16x8 nq[2];
            if (more) {
                const int nt0 = (chunk + (u + 1) * NCHUNK) * 64;
#pragma unroll
                for (int j = 0; j < 2; j++) {
                    const int f = tid + j * 256;
                    const int row = f >> 3, c8 = f & 7;
                    nq[j] = *(const bf16x8*)&qb[(size_t)(nt0 + row) * H_DIM + c8 * 8];
                }
            }

            const int t0 = (chunk + u * NCHUNK) * 64;
            bf16x8 a0 = *(const bf16x8*)&Qt[bi][wave * 16 + l15][quad * 8];
            bf16x8 a1 = *(const bf16x8*)&Qt[bi][wave * 16 + l15][32 + quad * 8];
#pragma unroll
            for (int sg = 0; sg < 4; sg++) {
                bf16x8 k0 = *(const bf16x8*)&Kt[sg * 16 + l15][quad * 8];
                bf16x8 k1 = *(const bf16x8*)&Kt[sg * 16 + l15][32 + quad * 8];
                f32x4 c4 = f32x4{0.f, 0.f, 0.f, 0.f};
                c4 = MFMA16(a0, k0, c4);
                c4 = MFMA16(a1, k1, c4);
                const int s = s0 + sg * 16 + l15;
#pragma unroll
                for (int r = 0; r < 4; r++) {
                    const int t = t0 + wave * 16 + quad * 4 + r;
                    const float e = __expf(c4[r]);
                    lloc[sg] += (t >= s) ? e : 0.0f;
                }
            }

            if (more) {
#pragma unroll
                for (int j = 0; j < 2; j++) {
                    const int f = tid + j * 256;
                    const int row = f >> 3, c8 = f & 7;
                    *(bf16x8*)&Qt[1 - bi][row][c8 * 8] = nq[j];
                }
            }
            __syncthreads();
        }
    } else {
        __syncthreads();
    }

#pragma unroll
    for (int sg = 0; sg < 4; sg++) {
        lloc[sg] += __shfl_xor(lloc[sg], 16);
        lloc[sg] += __shfl_xor(lloc[sg], 32);
        if (quad == 0) sl[wave][sg * 16 + l15] = lloc[sg];
    }
    __syncthreads();
    if (tid < 64) {
        const float L = sl[0][tid] + sl[1][tid] + sl[2][tid] + sl[3][tid];
        pl[(size_t)chunk * NTOK + b * T_SEQ + s0 + tid] = L;
    }
}

// ---------------------------------------------------------------------------
// vprep: merge NCHUNK partial column sums, scale V rows by 1/L, write V'
// transposed to global vT [b][h][t].
// ---------------------------------------------------------------------------
__global__ __launch_bounds__(256) void vprep_kernel(
    const float* __restrict__ pl, const short* __restrict__ vg,
    short* __restrict__ vTg)
{
    const int j0 = blockIdx.x;
    const int b  = blockIdx.y;
    const int s0 = j0 * 64;
    const int tid = threadIdx.x;

    __shared__ float lrec[64];
    __shared__ short Tt[64][72];

    if (tid < 64) {
        const int col = b * T_SEQ + s0 + tid;
        float L = 0.f;
#pragma unroll
        for (int c = 0; c < NCHUNK; c++) L += pl[(size_t)c * NTOK + col];
        lrec[tid] = 1.0f / L;
    }
    __syncthreads();

    const int sr = tid >> 3;
    const int sc = (tid & 7) * 8;
#pragma unroll
    for (int hh = 0; hh < 2; hh++) {
        const int s = sr + hh * 32;
        bf16x8 v = *(const bf16x8*)&vg[(size_t)(b * T_SEQ + s0 + s) * H_DIM + sc];
        const float li = lrec[s];
        bf16x8 o;
#pragma unroll
        for (int d = 0; d < 8; d++) o[d] = f2bf(bf2f(v[d]) * li);
        *(bf16x8*)&Tt[s][sc] = o;
    }
    __syncthreads();

#pragma unroll
    for (int hh = 0; hh < 2; hh++) {
        const int h = sr + hh * 32;
        bf16x8 o;
#pragma unroll
        for (int d = 0; d < 8; d++) o[d] = Tt[sc + d][h];
        *(bf16x8*)&vTg[(size_t)(b * H_DIM + h) * T_SEQ + s0 + sc] = o;
    }
}

// ---------------------------------------------------------------------------
// Output (R10 structure; NCHUNK=4 => up to 8 u-iters, half the atomics).
// ---------------------------------------------------------------------------
__global__ __launch_bounds__(256) void out_kernel(
    const short* __restrict__ qg, const short* __restrict__ kg,
    const short* __restrict__ vTg, float* __restrict__ outg)
{
    const int i0 = blockIdx.x, chunk = blockIdx.y, b = blockIdx.z;
    if (chunk > i0) return;
    const int t0 = i0 * 64;
    const short* __restrict__ qb  = qg  + (size_t)b * T_SEQ * H_DIM;
    const short* __restrict__ kb  = kg  + (size_t)b * T_SEQ * H_DIM;
    const short* __restrict__ vTb = vTg + (size_t)b * H_DIM * T_SEQ;
    const int tid = threadIdx.x, wave = tid >> 6, lane = tid & 63;
    const int l15 = lane & 15, quad = lane >> 4;

    __shared__ short Kt[2][64][72];
    __shared__ short Vt[2][64][72];
    __shared__ short PW[4][16][72];

    const int sh = tid >> 3;
    const int sc = (tid & 7) * 8;

    const short* qr = &qb[(size_t)(t0 + wave * 16 + l15) * H_DIM + quad * 8];
    const bf16x8 qa0 = *(const bf16x8*)qr;
    const bf16x8 qa1 = *(const bf16x8*)(qr + 32);

    f32x4 oacc[4];
#pragma unroll
    for (int hg = 0; hg < 4; hg++) oacc[hg] = f32x4{0.f, 0.f, 0.f, 0.f};

    {
        const int s0 = chunk * 64;
        *(bf16x8*)&Kt[0][sh][sc]      = *(const bf16x8*)&kb[(size_t)(s0 + sh) * H_DIM + sc];
        *(bf16x8*)&Kt[0][sh + 32][sc] = *(const bf16x8*)&kb[(size_t)(s0 + sh + 32) * H_DIM + sc];
        *(bf16x8*)&Vt[0][sh][sc]      = *(const bf16x8*)&vTb[(size_t)sh * T_SEQ + s0 + sc];
        *(bf16x8*)&Vt[0][sh + 32][sc] = *(const bf16x8*)&vTb[(size_t)(sh + 32) * T_SEQ + s0 + sc];
    }
    __syncthreads();

    for (int u = 0; u < NU; u++) {
        const int js = chunk + u * NCHUNK;
        if (js > i0) break;            // uniform per block
        const int s0 = js * 64;
        const int bi = u & 1;
        const bool more = (js + NCHUNK <= i0);

        bf16x8 nk0, nk1, nv0, nv1;
        if (more) {
            const int ns0 = s0 + NCHUNK * 64;
            nk0 = *(const bf16x8*)&kb[(size_t)(ns0 + sh) * H_DIM + sc];
            nk1 = *(const bf16x8*)&kb[(size_t)(ns0 + sh + 32) * H_DIM + sc];
            nv0 = *(const bf16x8*)&vTb[(size_t)sh * T_SEQ + ns0 + sc];
            nv1 = *(const bf16x8*)&vTb[(size_t)(sh + 32) * T_SEQ + ns0 + sc];
        }

        f32x4 c4[4];
#pragma unroll
        for (int sg = 0; sg < 4; sg++) {
            bf16x8 k0 = *(const bf16x8*)&Kt[bi][sg * 16 + l15][quad * 8];
            bf16x8 k1 = *(const bf16x8*)&Kt[bi][sg * 16 + l15][32 + quad * 8];
            f32x4 z = f32x4{0.f, 0.f, 0.f, 0.f};
            z = MFMA16(qa0, k0, z);
            z = MFMA16(qa1, k1, z);
            c4[sg] = z;
        }
#pragma unroll
        for (int sg = 0; sg < 4; sg++) {
            const int s = s0 + sg * 16 + l15;
#pragma unroll
            for (int r = 0; r < 4; r++) {
                const int t = t0 + wave * 16 + quad * 4 + r;
                const float p = (s <= t) ? __expf(c4[sg][r]) : 0.0f;
                PW[wave][quad * 4 + r][sg * 16 + l15] = f2bf(p);
            }
        }
        __syncthreads();

        const bf16x8 pa0 = *(const bf16x8*)&PW[wave][l15][quad * 8];
        const bf16x8 pa1 = *(const bf16x8*)&PW[wave][l15][32 + quad * 8];
#pragma unroll
        for (int hg = 0; hg < 4; hg++) {
            bf16x8 v0 = *(const bf16x8*)&Vt[bi][hg * 16 + l15][quad * 8];
            bf16x8 v1 = *(const bf16x8*)&Vt[bi][hg * 16 + l15][32 + quad * 8];
            oacc[hg] = MFMA16(pa0, v0, oacc[hg]);
            oacc[hg] = MFMA16(pa1, v1, oacc[hg]);
        }

        if (more) {
            *(bf16x8*)&Kt[1 - bi][sh][sc]      = nk0;
            *(bf16x8*)&Kt[1 - bi][sh + 32][sc] = nk1;
            *(bf16x8*)&Vt[1 - bi][sh][sc]      = nv0;
            *(bf16x8*)&Vt[1 - bi][sh + 32][sc] = nv1;
        }
        __syncthreads();
    }

#pragma unroll
    for (int hg = 0; hg < 4; hg++)
#pragma unroll
        for (int r = 0; r < 4; r++) {
            const int t = t0 + wave * 16 + quad * 4 + r;
            atomicAdd(&outg[(size_t)(b * T_SEQ + t) * H_DIM + hg * 16 + l15],
                      oacc[hg][r]);
        }
}

// ---------------------------------------------------------------------------
extern "C" void kernel_launch(void* const* d_in, const int* in_sizes, int n_in,
                              void* d_out, int out_size, void* d_ws, size_t ws_size,
                              hipStream_t stream) {
    const float* x  = (const float*)d_in[0];
    const float* Wq = (const float*)d_in[1];
    const float* Wk = (const float*)d_in[2];
    const float* Wv = (const float*)d_in[3];
    float* out = (float*)d_out;

    float* w = (float*)d_ws;
    float* pl = w;                            // NCHUNK*NTOK
    short* qb = (short*)(pl + (size_t)NCHUNK * NTOK);
    short* kb = qb + (size_t)NTOK * H_DIM;
    short* vb = kb + (size_t)NTOK * H_DIM;
    short* Wb = vb + (size_t)NTOK * H_DIM;    // [3][H*C]
    short* vT = Wb + (size_t)3 * H_DIM * C_DIM;  // [B][H][T]

    prep_kernel<<<96 + (NTOK * H_DIM / 4) / 256, 256, 0, stream>>>(
        Wq, Wk, Wv, Wb, (float4*)out);
    // R14: fused proj, 768 threads (12 waves = 3/SIMD); dynamic LDS 73728 B
    const size_t proj_lds = (size_t)(2 * 64 * 72 + 2 * 3 * 64 * 72) * sizeof(short);
    proj_kernel<<<256, 768, proj_lds, stream>>>(x, Wb, qb, kb, vb);
    stats_kernel<<<dim3(NTILE, NCHUNK, N_BATCH), 256, 0, stream>>>(qb, kb, pl);
    vprep_kernel<<<dim3(NTILE, N_BATCH), 256, 0, stream>>>(pl, vb, vT);
    out_kernel<<<dim3(NTILE, NCHUNK, N_BATCH), 256, 0, stream>>>(qb, kb, vT, out);
}